// Round 10
// baseline (64.462 us; speedup 1.0000x reference)
//
#include <hip/hip_runtime.h>
#include <hip/hip_bf16.h>

namespace {

constexpr int B_ = 4, L = 2048, H = 8, E = 64;
constexpr int RS = H * E;            // 512 floats: row stride in [B,L,H,E]
constexpr float CS = 0.125f * 1.44269504f;  // SCALE * log2(e): exp2-direct
constexpr float THR2 = 11.5f;        // defer-max threshold in log2 units

constexpr size_t TILE_BYTES = 8192;                    // one 64-key image (K or V)
constexpr size_t NTILES = 32 * 32;                     // (bh, tile)
constexpr size_t KIMG_BYTES = NTILES * TILE_BYTES;     // 8.4 MB
constexpr size_t IMG_FLOATS = 2 * KIMG_BYTES / 4;      // K + V images

// split-K partials (floats): acc[2][32][8][128][64] ++ m ++ l
constexpr size_t ACCF = (size_t)2 * 32 * 8 * 128 * 64;
constexpr size_t MOFF = ACCF;
constexpr size_t PART_ROWS = (size_t)32 * 8 * 128;
constexpr size_t LOFF = MOFF + 2 * PART_ROWS;
constexpr size_t PART_FLOATS = LOFF + 2 * PART_ROWS;   // ~17.3 MB

typedef __attribute__((ext_vector_type(8))) short bf16x8;
typedef __attribute__((ext_vector_type(4))) float f32x4;

__device__ inline unsigned cvt2(float a, float b) {
  __hip_bfloat162 hh = __float22bfloat162_rn(make_float2(a, b));  // v_cvt_pk_bf16_f32
  union { __hip_bfloat162 h; unsigned u; } c; c.h = hh; return c.u;
}

// One-time fp32 -> bf16 repack into LDS-image layout (bit-exact what the old
// stage_write produced): K image [key][128B] chunk c at 16*(c^(key&7)) holds
// dims 8c..8c+7; V image [dim][128B] chunk c at 16*(c^(dim&7)) holds keys
// 8c..8c+7 (transposed).
__global__ __launch_bounds__(256)
void repack(const float* __restrict__ K, const float* __restrict__ V,
            unsigned char* __restrict__ img)
{
  const int tid = (int)threadIdx.x;
  const int bi  = (int)blockIdx.x;       // 0..1023
  const int bh  = bi & 31, t = bi >> 5;
  const int b = bh >> 3, h = bh & 7;
  const size_t base = (size_t)b * L * RS + (size_t)h * E;
  const int kv0 = t * 64;
  const int row = tid >> 2, c0 = (tid & 3) * 2;   // row 0..63, chunks c0,c0+1

  unsigned char* Kimg = img + (size_t)(bh * 32 + t) * TILE_BYTES;
  unsigned char* Vimg = img + KIMG_BYTES + (size_t)(bh * 32 + t) * TILE_BYTES;

  {  // K: row = key, dims 16*(tid&3) .. +15
    const float4* kp = (const float4*)(K + base + (size_t)(kv0 + row) * RS + 8 * c0);
    const float4 a = kp[0], bq = kp[1], c = kp[2], d = kp[3];
    uint4 w0; w0.x = cvt2(a.x, a.y);  w0.y = cvt2(a.z, a.w);
              w0.z = cvt2(bq.x, bq.y); w0.w = cvt2(bq.z, bq.w);
    uint4 w1; w1.x = cvt2(c.x, c.y);  w1.y = cvt2(c.z, c.w);
              w1.z = cvt2(d.x, d.y);  w1.w = cvt2(d.z, d.w);
    *(uint4*)(Kimg + row * 128 + 16 * (c0 ^ (row & 7)))       = w0;
    *(uint4*)(Kimg + row * 128 + 16 * ((c0 + 1) ^ (row & 7))) = w1;
  }
  {  // V: row = dim, keys 8c0..8c0+15
    const float* vp = V + base + (size_t)(kv0 + 8 * c0) * RS + row;
    float v[16];
#pragma unroll
    for (int j = 0; j < 16; ++j) v[j] = vp[(size_t)j * RS];
    uint4 w0; w0.x = cvt2(v[0], v[1]);   w0.y = cvt2(v[2], v[3]);
              w0.z = cvt2(v[4], v[5]);   w0.w = cvt2(v[6], v[7]);
    uint4 w1; w1.x = cvt2(v[8], v[9]);   w1.y = cvt2(v[10], v[11]);
              w1.z = cvt2(v[12], v[13]); w1.w = cvt2(v[14], v[15]);
    *(uint4*)(Vimg + row * 128 + 16 * (c0 ^ (row & 7)))       = w0;
    *(uint4*)(Vimg + row * 128 + 16 * ((c0 + 1) ^ (row & 7))) = w1;
  }
}

// Block = 8 waves, KVBLK=64. Pair (g, 15-g) of 128-row q-groups: step counts
// (2g+2) + (32-2g) = 34 -> two roles of EXACTLY 17 steps (equal makespan).
// role 0: group g complete, then head of v=15-g -> partial(part 0).
// role 1: tail 17 steps of v -> partial(part 1). role 2 (no-ws fallback): 34.
// Swapped S^T = K*Q^T; exp2-domain softmax (scale folded into Q).
// PACKED: staging = 2 x global_load_lds(16B) from pre-swizzled bf16 images
// (linear LDS dest = wave-uniform base + lane*16; swizzle lives in the image).
template<bool PACKED>
__global__ __launch_bounds__(512)
void fa_split(const float* __restrict__ Q, const float* __restrict__ K,
              const float* __restrict__ V, float* __restrict__ O,
              const unsigned char* __restrict__ img,
              float* __restrict__ ws, int splitMode)
{
  const int tid  = (int)threadIdx.x;
  const int lane = tid & 63;
  const int wv   = tid >> 6;
  const int bi   = (int)blockIdx.x;
  const int bh   = bi & 31;                 // low bits -> XCD L2 locality
  const int pp   = (bi >> 5) & 7;
  const int role = splitMode ? (bi >> 8) : 2;
  const int b = bh >> 3, h = bh & 7;
  const int ln = lane & 15, lg = lane >> 4, d0 = lg * 4;

  // schedule (64-key steps)
  int total, ph1sb0, qgA, k0A, qgB; bool finA, finB; int part;
  const int g = pp, v = 15 - pp;
  if (role == 0)      { total = 17; ph1sb0 = 2*g+2; qgA = g; k0A = 0;        finA = true;  qgB = v; finB = false; part = 0; }
  else if (role == 1) { total = 17; ph1sb0 = 1000;  qgA = v; k0A = 15 - 2*g; finA = false; qgB = 0; finB = false; part = 1; }
  else                { total = 34; ph1sb0 = 2*g+2; qgA = g; k0A = 0;        finA = true;  qgB = v; finB = true;  part = 0; }

  const size_t base = (size_t)b * L * RS + (size_t)h * E;
  const float* Qb = Q + base;
  const float* Kb = K + base;
  const float* Vb = V + base;
  float*       Ob = O + base;

  __shared__ __align__(16) unsigned char KT[2][64 * 128]; // [key][dim*2B], swz
  __shared__ __align__(16) unsigned char VT[2][64 * 128]; // [dim][key*2B], swz

  // ---- staging (PACKED): async image -> LDS, swizzle pre-applied ----
  auto stage_issue = [&](int ks, int bufI) {
    const unsigned char* kg = img + (size_t)(bh * 32 + ks) * TILE_BYTES + tid * 16;
    const unsigned char* vg = img + KIMG_BYTES + (size_t)(bh * 32 + ks) * TILE_BYTES + tid * 16;
    __builtin_amdgcn_global_load_lds(
        (const __attribute__((address_space(1))) void*)kg,
        (__attribute__((address_space(3))) void*)(&KT[bufI][tid * 16]), 16, 0, 0);
    __builtin_amdgcn_global_load_lds(
        (const __attribute__((address_space(1))) void*)vg,
        (__attribute__((address_space(3))) void*)(&VT[bufI][tid * 16]), 16, 0, 0);
  };

  // ---- staging (fallback): fp32 load -> cvt -> swizzled ds_write ----
  const int vdd = tid & 63, vkq = tid >> 6;   // V: dim vdd, keys 8vkq..+7
  const int kky = tid >> 3, kc  = tid & 7;    // K: key kky, dims 8kc..+7
  float vr[8]; float4 kr0, kr1;

  auto stage_load = [&](int ks) {
    const int kv0 = ks * 64;
    const float* vp = Vb + (size_t)(kv0 + 8 * vkq) * RS + vdd;
#pragma unroll
    for (int j = 0; j < 8; ++j) vr[j] = vp[(size_t)j * RS];
    const float* kp = Kb + (size_t)(kv0 + kky) * RS + 8 * kc;
    kr0 = *(const float4*)kp; kr1 = *(const float4*)(kp + 4);
  };
  auto stage_write = [&](int bufI) {
    union { uint4 q; unsigned u[4]; } w;
    w.u[0] = cvt2(vr[0], vr[1]); w.u[1] = cvt2(vr[2], vr[3]);
    w.u[2] = cvt2(vr[4], vr[5]); w.u[3] = cvt2(vr[6], vr[7]);
    *(uint4*)(VT[bufI] + vdd * 128 + 16 * (vkq ^ (vdd & 7))) = w.q;
    union { uint4 q; unsigned u[4]; } y;
    y.u[0] = cvt2(kr0.x, kr0.y); y.u[1] = cvt2(kr0.z, kr0.w);
    y.u[2] = cvt2(kr1.x, kr1.y); y.u[3] = cvt2(kr1.z, kr1.w);
    *(uint4*)(KT[bufI] + kky * 128 + 16 * (kc ^ (kky & 7))) = y.q;
  };

  // ---- per-phase state ----
  int qg = qgA; bool curFin = finA;
  int qrow0 = qg * 128 + wv * 16;
  int nsW   = (qrow0 + 79) >> 6;             // 64-key steps this wave needs

  bf16x8 qf0, qf1;
  auto load_q = [&]() {                      // Q pre-scaled by CS (exp2 domain)
    const float* qp = Qb + (size_t)(qrow0 + ln) * RS + 8 * lg;
    float4 a = *(const float4*)qp,        c = *(const float4*)(qp + 4);
    float4 d = *(const float4*)(qp + 32), e = *(const float4*)(qp + 36);
    union { bf16x8 v8; unsigned u[4]; } r0, r1;
    r0.u[0] = cvt2(a.x * CS, a.y * CS); r0.u[1] = cvt2(a.z * CS, a.w * CS);
    r0.u[2] = cvt2(c.x * CS, c.y * CS); r0.u[3] = cvt2(c.z * CS, c.w * CS);
    r1.u[0] = cvt2(d.x * CS, d.y * CS); r1.u[1] = cvt2(d.z * CS, d.w * CS);
    r1.u[2] = cvt2(e.x * CS, e.y * CS); r1.u[3] = cvt2(e.z * CS, e.w * CS);
    qf0 = r0.v8; qf1 = r1.v8;
  };
  load_q();

  f32x4 acc[4];
#pragma unroll
  for (int nt = 0; nt < 4; ++nt) acc[nt] = (f32x4){0.f, 0.f, 0.f, 0.f};
  float m = -1e30f, lsum = 0.f;

  auto epilogue = [&]() {
    if (curFin) {
      const float il = 1.0f / lsum;
      float inv[4];
#pragma unroll
      for (int r = 0; r < 4; ++r) inv[r] = __shfl(il, d0 + r, 64);
#pragma unroll
      for (int nt = 0; nt < 4; ++nt)
#pragma unroll
        for (int r = 0; r < 4; ++r)
          Ob[(size_t)(qrow0 + d0 + r) * RS + (ln + 16 * nt)] = acc[nt][r] * inv[r];
    } else {
      const int vg = qg - 8;
      const size_t rb = ((size_t)part * 32 + bh) * 1024 + (size_t)vg * 128;
#pragma unroll
      for (int nt = 0; nt < 4; ++nt)
#pragma unroll
        for (int r = 0; r < 4; ++r)
          ws[(rb + wv * 16 + d0 + r) * 64 + ln + 16 * nt] = acc[nt][r];
      if (lane < 16) {
        ws[MOFF + rb + wv * 16 + lane] = m;
        ws[LOFF + rb + wv * 16 + lane] = lsum;
      }
    }
  };

  if constexpr (PACKED) {
    stage_issue(k0A, 0);
  } else {
    stage_load(k0A);
    stage_write(0);
  }
  __syncthreads();
  int buf = 0;

  for (int sb = 0; sb < total; ++sb) {
    const bool haveNext = (sb + 1) < total;
    if (haveNext) {
      const int sn = sb + 1;
      const int nks = (sn < ph1sb0) ? (k0A + sn) : (sn - ph1sb0);
      if constexpr (PACKED) stage_issue(nks, buf ^ 1);   // async into other buf
      else                  stage_load(nks);             // T14: issue early
    }
    const int kstep = (sb < ph1sb0) ? (k0A + sb) : (sb - ph1sb0);

    if (kstep < nsW) {
      const unsigned char* Kt = KT[buf];
      const int swzr = 16 * (ln & 7);        // (16kt+ln)&7 == ln&7

      // ---- QK^T: 4 key-tiles x 2 dim-halves ----
      f32x4 st[4];
#pragma unroll
      for (int kt = 0; kt < 4; ++kt) {
        const unsigned char* kr = Kt + (16 * kt + ln) * 128;
        const bf16x8 kfa = *(const bf16x8*)(kr + ((16 * lg) ^ swzr));
        const bf16x8 kfb = *(const bf16x8*)(kr + ((16 * lg + 64) ^ swzr));
        f32x4 s = (f32x4){0.f, 0.f, 0.f, 0.f};
        s = __builtin_amdgcn_mfma_f32_16x16x32_bf16(kfa, qf0, s, 0, 0, 0);
        s = __builtin_amdgcn_mfma_f32_16x16x32_bf16(kfb, qf1, s, 0, 0, 0);
        st[kt] = s;
      }

      float x[16];
#pragma unroll
      for (int kt = 0; kt < 4; ++kt)
#pragma unroll
        for (int r = 0; r < 4; ++r) x[4 * kt + r] = st[kt][r];

      if (kstep == nsW - 1) {                // diagonal tile
        const int kv0 = kstep * 64;
        const int qr = qrow0 + ln;
#pragma unroll
        for (int kt = 0; kt < 4; ++kt)
#pragma unroll
          for (int r = 0; r < 4; ++r) {
            const int key = kv0 + 16 * kt + d0 + r;
            if (key > qr) x[4 * kt + r] = -1e30f;
          }
      }

      // ---- online softmax (exp2 domain) with defer-max ----
      float mx = x[0];
#pragma unroll
      for (int e = 1; e < 16; ++e) mx = fmaxf(mx, x[e]);
      mx = fmaxf(mx, __shfl_xor(mx, 16, 64));
      mx = fmaxf(mx, __shfl_xor(mx, 32, 64));

      if (!__all(mx <= m + THR2)) {
        const float newm = fmaxf(m, mx);
        const float sc = __builtin_exp2f(m - newm);
        lsum *= sc;
        float scr[4];
#pragma unroll
        for (int r = 0; r < 4; ++r) scr[r] = __shfl(sc, d0 + r, 64);
#pragma unroll
        for (int nt = 0; nt < 4; ++nt) {
          acc[nt][0] *= scr[0]; acc[nt][1] *= scr[1];
          acc[nt][2] *= scr[2]; acc[nt][3] *= scr[3];
        }
        m = newm;
      }

      float p[16]; float ps = 0.f;
#pragma unroll
      for (int e = 0; e < 16; ++e) { p[e] = __builtin_exp2f(x[e] - m); ps += p[e]; }
      ps += __shfl_xor(ps, 16, 64);
      ps += __shfl_xor(ps, 32, 64);
      lsum += ps;

      // ---- PV: 2 key-groups x 4 dim-tiles ----
      const unsigned char* Vt = VT[buf];
#pragma unroll
      for (int kg = 0; kg < 2; ++kg) {
        union { bf16x8 v8; unsigned u[4]; } pf;
#pragma unroll
        for (int j = 0; j < 4; ++j)
          pf.u[j] = cvt2(p[8 * kg + 2 * j], p[8 * kg + 2 * j + 1]);
#pragma unroll
        for (int nt = 0; nt < 4; ++nt) {
          const int row = ln + 16 * nt;
          const unsigned char* vrow = Vt + row * 128;
          const int sz = 16 * (row & 7);
          union { bf16x8 v8; uint2 p2[2]; } vf;
          vf.p2[0] = *(const uint2*)(vrow + ((8 * lg + 64 * kg) ^ sz));
          vf.p2[1] = *(const uint2*)(vrow + ((8 * lg + 32 + 64 * kg) ^ sz));
          acc[nt] = __builtin_amdgcn_mfma_f32_16x16x32_bf16(pf.v8, vf.v8, acc[nt], 0, 0, 0);
        }
      }
    }

    if (sb == ph1sb0 - 1) {                  // phase boundary (block-uniform)
      epilogue();
#pragma unroll
      for (int nt = 0; nt < 4; ++nt) acc[nt] = (f32x4){0.f, 0.f, 0.f, 0.f};
      m = -1e30f; lsum = 0.f;
      qg = qgB; curFin = finB;
      qrow0 = qg * 128 + wv * 16;
      nsW = (qrow0 + 79) >> 6;
      load_q();
    }

    if constexpr (!PACKED) { if (haveNext) stage_write(buf ^ 1); }
    __syncthreads();
    buf ^= 1;
  }

  epilogue();
}

// Combine the two split-K partials for v-rows (groups 8..15); m is log2-domain.
__global__ __launch_bounds__(256)
void fa_merge(const float* __restrict__ ws, float* __restrict__ O)
{
  const int idx = (int)blockIdx.x * 256 + (int)threadIdx.x;   // 0..524287
  const int d4  = idx & 15;
  const int row = (idx >> 4) & 127;
  const int vg  = (idx >> 11) & 7;
  const int bh  = idx >> 14;
  const size_t rbase = ((size_t)bh * 8 + vg) * 128 + row;

  const float m0 = ws[MOFF + rbase],             l0 = ws[LOFF + rbase];
  const float m1 = ws[MOFF + PART_ROWS + rbase], l1 = ws[LOFF + PART_ROWS + rbase];
  const float M  = fmaxf(m0, m1);
  const float e0 = __builtin_exp2f(m0 - M), e1 = __builtin_exp2f(m1 - M);
  const float inv = 1.0f / (l0 * e0 + l1 * e1);

  const float4 a0 = *(const float4*)(ws + rbase * 64 + 4 * d4);
  const float4 a1 = *(const float4*)(ws + PART_ROWS * 64 + rbase * 64 + 4 * d4);

  const int b = bh >> 3, h = bh & 7;
  const int orow = (8 + vg) * 128 + row;
  float4 o;
  o.x = (a0.x * e0 + a1.x * e1) * inv;
  o.y = (a0.y * e0 + a1.y * e1) * inv;
  o.z = (a0.z * e0 + a1.z * e1) * inv;
  o.w = (a0.w * e0 + a1.w * e1) * inv;
  *(float4*)(O + ((size_t)(b * L + orow) * H + h) * E + 4 * d4) = o;
}

} // namespace

extern "C" void kernel_launch(void* const* d_in, const int* in_sizes, int n_in,
                              void* d_out, int out_size, void* d_ws, size_t ws_size,
                              hipStream_t stream) {
  const float* Q = (const float*)d_in[0];
  const float* K = (const float*)d_in[1];
  const float* V = (const float*)d_in[2];
  float* O = (float*)d_out;
  (void)in_sizes; (void)n_in; (void)out_size;

  const bool full = ws_size >= (IMG_FLOATS + PART_FLOATS) * sizeof(float);
  const bool mid  = ws_size >= PART_FLOATS * sizeof(float);
  if (full) {
    repack<<<1024, 256, 0, stream>>>(K, V, (unsigned char*)d_ws);
    float* parts = (float*)d_ws + IMG_FLOATS;
    fa_split<true><<<512, 512, 0, stream>>>(Q, K, V, O, (const unsigned char*)d_ws, parts, 1);
    fa_merge<<<2048, 256, 0, stream>>>(parts, O);
  } else if (mid) {
    fa_split<false><<<512, 512, 0, stream>>>(Q, K, V, O, nullptr, (float*)d_ws, 1);
    fa_merge<<<2048, 256, 0, stream>>>((const float*)d_ws, O);
  } else {
    fa_split<false><<<256, 512, 0, stream>>>(Q, K, V, O, nullptr, (float*)d_ws, 0);
  }
}

// Round 11
// 53.141 us; speedup vs baseline: 1.2130x; 1.2130x over previous
//
#include <hip/hip_runtime.h>
#include <hip/hip_bf16.h>

namespace {

constexpr int B_ = 4, L = 2048, H = 8, E = 64;
constexpr int RS = H * E;            // 512 floats: row stride in [B,L,H,E]
constexpr float CS = 0.125f * 1.44269504f;  // SCALE * log2(e): exp2-direct
constexpr float THR2 = 11.5f;        // defer-max threshold in log2 units

// split-K partials (floats): acc[2][32][8][128][64] ++ m ++ l
constexpr size_t ACCF = (size_t)2 * 32 * 8 * 128 * 64;
constexpr size_t MOFF = ACCF;
constexpr size_t PART_ROWS = (size_t)32 * 8 * 128;
constexpr size_t LOFF = MOFF + 2 * PART_ROWS;
constexpr size_t PART_FLOATS = LOFF + 2 * PART_ROWS;   // ~17.3 MB

typedef __attribute__((ext_vector_type(8))) short bf16x8;
typedef __attribute__((ext_vector_type(4))) float f32x4;

__device__ inline unsigned cvt2(float a, float b) {
  __hip_bfloat162 hh = __float22bfloat162_rn(make_float2(a, b));  // v_cvt_pk_bf16_f32
  union { __hip_bfloat162 h; unsigned u; } c; c.h = hh; return c.u;
}

// Block = 8 waves, KVBLK=64. Pair (g, 15-g) of 128-row q-groups: step counts
// (2g+2) + (32-2g) = 34 -> two roles of EXACTLY 17 steps (equal makespan).
// role 0: group g complete, then head of v=15-g -> partial(part 0).
// role 1: tail 17 steps of v -> partial(part 1). role 2 (no-ws fallback): 34.
// Swapped S^T = K*Q^T; exp2-domain softmax (scale folded into Q).
// Per-lane lsum partials (no per-step cross-lane reduce); group reduce only on
// rare rescale events and in the epilogue.
// K LDS [key][128B]: chunk c at 16*(c^(key&7)) = dims 8c..8c+7.
// V LDS [dim][128B]: chunk c at 16*(c^(dim&7)) = keys {4c..4c+3,16+4c..+3}
// (c<4; +32 for c>=4) -> V fragment read is ONE ds_read_b128, slot order
// exactly matches the P fragment.
__global__ __launch_bounds__(512)
void fa_split(const float* __restrict__ Q, const float* __restrict__ K,
              const float* __restrict__ V, float* __restrict__ O,
              float* __restrict__ ws, int splitMode)
{
  const int tid  = (int)threadIdx.x;
  const int lane = tid & 63;
  const int wv   = tid >> 6;
  const int bi   = (int)blockIdx.x;
  const int bh   = bi & 31;                 // low bits -> XCD L2 locality
  const int pp   = (bi >> 5) & 7;
  const int role = splitMode ? (bi >> 8) : 2;
  const int b = bh >> 3, h = bh & 7;
  const int ln = lane & 15, lg = lane >> 4, d0 = lg * 4;

  // schedule (64-key steps)
  int total, ph1sb0, qgA, k0A, qgB; bool finA, finB; int part;
  const int g = pp, v = 15 - pp;
  if (role == 0)      { total = 17; ph1sb0 = 2*g+2; qgA = g; k0A = 0;        finA = true;  qgB = v; finB = false; part = 0; }
  else if (role == 1) { total = 17; ph1sb0 = 1000;  qgA = v; k0A = 15 - 2*g; finA = false; qgB = 0; finB = false; part = 1; }
  else                { total = 34; ph1sb0 = 2*g+2; qgA = g; k0A = 0;        finA = true;  qgB = v; finB = true;  part = 0; }

  const size_t base = (size_t)b * L * RS + (size_t)h * E;
  const float* Qb = Q + base;
  const float* Kb = K + base;
  const float* Vb = V + base;
  float*       Ob = O + base;

  __shared__ __align__(16) unsigned char KT[2][64 * 128];
  __shared__ __align__(16) unsigned char VT[2][64 * 128];

  // ---- staging: 512 threads stage both V and K (one uint4 write each) ----
  const int vdd = tid & 63, vc = tid >> 6;          // V: dim vdd, chunk vc
  const int vkb = 4 * vc + ((vc >> 2) << 4);        // keys vkb..+3, vkb+16..+19
  const int kky = tid >> 3, kc = tid & 7;           // K: key kky, dims 8kc..+7
  float vr[8]; float4 kr0, kr1;

  auto stage_load = [&](int ks) {
    const int kv0 = ks * 64;
    const float* vp = Vb + (size_t)(kv0 + vkb) * RS + vdd;
#pragma unroll
    for (int j = 0; j < 4; ++j) vr[j] = vp[(size_t)j * RS];
#pragma unroll
    for (int j = 0; j < 4; ++j) vr[4 + j] = vp[(size_t)(16 + j) * RS];
    const float* kp = Kb + (size_t)(kv0 + kky) * RS + 8 * kc;
    kr0 = *(const float4*)kp; kr1 = *(const float4*)(kp + 4);
  };
  auto stage_write = [&](int bufI) {
    union { uint4 q; unsigned u[4]; } w;
    w.u[0] = cvt2(vr[0], vr[1]); w.u[1] = cvt2(vr[2], vr[3]);
    w.u[2] = cvt2(vr[4], vr[5]); w.u[3] = cvt2(vr[6], vr[7]);
    *(uint4*)(VT[bufI] + vdd * 128 + 16 * (vc ^ (vdd & 7))) = w.q;
    union { uint4 q; unsigned u[4]; } y;
    y.u[0] = cvt2(kr0.x, kr0.y); y.u[1] = cvt2(kr0.z, kr0.w);
    y.u[2] = cvt2(kr1.x, kr1.y); y.u[3] = cvt2(kr1.z, kr1.w);
    *(uint4*)(KT[bufI] + kky * 128 + 16 * (kc ^ (kky & 7))) = y.q;
  };

  // ---- per-phase state ----
  int qg = qgA; bool curFin = finA;
  int qrow0 = qg * 128 + wv * 16;
  int nsW   = (qrow0 + 79) >> 6;             // 64-key steps this wave needs

  bf16x8 qf0, qf1;
  auto load_q = [&]() {                      // Q pre-scaled by CS (exp2 domain)
    const float* qp = Qb + (size_t)(qrow0 + ln) * RS + 8 * lg;
    float4 a = *(const float4*)qp,        c = *(const float4*)(qp + 4);
    float4 d = *(const float4*)(qp + 32), e = *(const float4*)(qp + 36);
    union { bf16x8 v8; unsigned u[4]; } r0, r1;
    r0.u[0] = cvt2(a.x * CS, a.y * CS); r0.u[1] = cvt2(a.z * CS, a.w * CS);
    r0.u[2] = cvt2(c.x * CS, c.y * CS); r0.u[3] = cvt2(c.z * CS, c.w * CS);
    r1.u[0] = cvt2(d.x * CS, d.y * CS); r1.u[1] = cvt2(d.z * CS, d.w * CS);
    r1.u[2] = cvt2(e.x * CS, e.y * CS); r1.u[3] = cvt2(e.z * CS, e.w * CS);
    qf0 = r0.v8; qf1 = r1.v8;
  };
  load_q();

  f32x4 acc[4];
#pragma unroll
  for (int nt = 0; nt < 4; ++nt) acc[nt] = (f32x4){0.f, 0.f, 0.f, 0.f};
  float m = -1e30f, lsum = 0.f;              // lsum: PER-LANE partial

  auto epilogue = [&]() {
    float ls = lsum + __shfl_xor(lsum, 16, 64);   // row total (4 lane copies)
    ls += __shfl_xor(ls, 32, 64);
    if (curFin) {
      const float il = 1.0f / ls;
      float inv[4];
#pragma unroll
      for (int r = 0; r < 4; ++r) inv[r] = __shfl(il, d0 + r, 64);
#pragma unroll
      for (int nt = 0; nt < 4; ++nt)
#pragma unroll
        for (int r = 0; r < 4; ++r)
          Ob[(size_t)(qrow0 + d0 + r) * RS + (ln + 16 * nt)] = acc[nt][r] * inv[r];
    } else {
      const int vg = qg - 8;
      const size_t rb = ((size_t)part * 32 + bh) * 1024 + (size_t)vg * 128;
#pragma unroll
      for (int nt = 0; nt < 4; ++nt)
#pragma unroll
        for (int r = 0; r < 4; ++r)
          ws[(rb + wv * 16 + d0 + r) * 64 + ln + 16 * nt] = acc[nt][r];
      if (lane < 16) {
        ws[MOFF + rb + wv * 16 + lane] = m;
        ws[LOFF + rb + wv * 16 + lane] = ls;
      }
    }
  };

  stage_load(k0A);
  stage_write(0);
  __syncthreads();
  int buf = 0;

  for (int sb = 0; sb < total; ++sb) {
    const bool haveNext = (sb + 1) < total;
    if (haveNext) {
      const int sn = sb + 1;
      stage_load((sn < ph1sb0) ? (k0A + sn) : (sn - ph1sb0));   // T14: issue early
    }
    const int kstep = (sb < ph1sb0) ? (k0A + sb) : (sb - ph1sb0);

    if (kstep < nsW) {
      const unsigned char* Kt = KT[buf];
      const int swzr = 16 * (ln & 7);        // (16kt+ln)&7 == ln&7

      // ---- QK^T: 4 key-tiles x 2 dim-halves ----
      f32x4 st[4];
#pragma unroll
      for (int kt = 0; kt < 4; ++kt) {
        const unsigned char* kr = Kt + (16 * kt + ln) * 128;
        const bf16x8 kfa = *(const bf16x8*)(kr + ((16 * lg) ^ swzr));
        const bf16x8 kfb = *(const bf16x8*)(kr + ((16 * lg + 64) ^ swzr));
        f32x4 s = (f32x4){0.f, 0.f, 0.f, 0.f};
        s = __builtin_amdgcn_mfma_f32_16x16x32_bf16(kfa, qf0, s, 0, 0, 0);
        s = __builtin_amdgcn_mfma_f32_16x16x32_bf16(kfb, qf1, s, 0, 0, 0);
        st[kt] = s;
      }

      float x[16];
#pragma unroll
      for (int kt = 0; kt < 4; ++kt)
#pragma unroll
        for (int r = 0; r < 4; ++r) x[4 * kt + r] = st[kt][r];

      if (kstep == nsW - 1) {                // diagonal tile
        const int kv0 = kstep * 64;
        const int qr = qrow0 + ln;
#pragma unroll
        for (int kt = 0; kt < 4; ++kt)
#pragma unroll
          for (int r = 0; r < 4; ++r) {
            const int key = kv0 + 16 * kt + d0 + r;
            if (key > qr) x[4 * kt + r] = -1e30f;
          }
      }

      // ---- per-lane max (tree), rescale only on rare events ----
      float t8[8];
#pragma unroll
      for (int e = 0; e < 8; ++e) t8[e] = fmaxf(x[e], x[8 + e]);
      float t4a = fmaxf(t8[0], t8[4]), t4b = fmaxf(t8[1], t8[5]);
      float t4c = fmaxf(t8[2], t8[6]), t4d = fmaxf(t8[3], t8[7]);
      float mx = fmaxf(fmaxf(t4a, t4b), fmaxf(t4c, t4d));

      if (!__all(mx <= m + THR2)) {
        float gm = fmaxf(mx, __shfl_xor(mx, 16, 64));
        gm = fmaxf(gm, __shfl_xor(gm, 32, 64));
        const float newm = fmaxf(m, gm);
        const float sc = __builtin_exp2f(m - newm);
        lsum *= sc;
        float scr[4];
#pragma unroll
        for (int r = 0; r < 4; ++r) scr[r] = __shfl(sc, d0 + r, 64);
#pragma unroll
        for (int nt = 0; nt < 4; ++nt) {
          acc[nt][0] *= scr[0]; acc[nt][1] *= scr[1];
          acc[nt][2] *= scr[2]; acc[nt][3] *= scr[3];
        }
        m = newm;
      }

      float p[16];
#pragma unroll
      for (int e = 0; e < 16; ++e) p[e] = __builtin_exp2f(x[e] - m);
      {  // per-lane partial sum (tree); no cross-lane reduce here
        float s8[8];
#pragma unroll
        for (int e = 0; e < 8; ++e) s8[e] = p[e] + p[8 + e];
        float s4a = s8[0] + s8[4], s4b = s8[1] + s8[5];
        float s4c = s8[2] + s8[6], s4d = s8[3] + s8[7];
        lsum += (s4a + s4b) + (s4c + s4d);
      }

      // ---- PV: 2 key-groups x 4 dim-tiles, V frag = ONE b128 ----
      const unsigned char* Vt = VT[buf];
#pragma unroll
      for (int kg = 0; kg < 2; ++kg) {
        union { bf16x8 v8; unsigned u[4]; } pf;
#pragma unroll
        for (int j = 0; j < 4; ++j)
          pf.u[j] = cvt2(p[8 * kg + 2 * j], p[8 * kg + 2 * j + 1]);
#pragma unroll
        for (int nt = 0; nt < 4; ++nt) {
          const int row = ln + 16 * nt;
          const bf16x8 vf = *(const bf16x8*)(
              Vt + row * 128 + 16 * ((lg + 4 * kg) ^ (ln & 7)));
          acc[nt] = __builtin_amdgcn_mfma_f32_16x16x32_bf16(pf.v8, vf, acc[nt], 0, 0, 0);
        }
      }
    }

    if (sb == ph1sb0 - 1) {                  // phase boundary (block-uniform)
      epilogue();
#pragma unroll
      for (int nt = 0; nt < 4; ++nt) acc[nt] = (f32x4){0.f, 0.f, 0.f, 0.f};
      m = -1e30f; lsum = 0.f;
      qg = qgB; curFin = finB;
      qrow0 = qg * 128 + wv * 16;
      nsW = (qrow0 + 79) >> 6;
      load_q();
    }

    if (haveNext) stage_write(buf ^ 1);
    __syncthreads();
    buf ^= 1;
  }

  epilogue();
}

// Combine the two split-K partials for v-rows (groups 8..15); m is log2-domain.
__global__ __launch_bounds__(256)
void fa_merge(const float* __restrict__ ws, float* __restrict__ O)
{
  const int idx = (int)blockIdx.x * 256 + (int)threadIdx.x;   // 0..524287
  const int d4  = idx & 15;
  const int row = (idx >> 4) & 127;
  const int vg  = (idx >> 11) & 7;
  const int bh  = idx >> 14;
  const size_t rbase = ((size_t)bh * 8 + vg) * 128 + row;

  const float m0 = ws[MOFF + rbase],             l0 = ws[LOFF + rbase];
  const float m1 = ws[MOFF + PART_ROWS + rbase], l1 = ws[LOFF + PART_ROWS + rbase];
  const float M  = fmaxf(m0, m1);
  const float e0 = __builtin_exp2f(m0 - M), e1 = __builtin_exp2f(m1 - M);
  const float inv = 1.0f / (l0 * e0 + l1 * e1);

  const float4 a0 = *(const float4*)(ws + rbase * 64 + 4 * d4);
  const float4 a1 = *(const float4*)(ws + PART_ROWS * 64 + rbase * 64 + 4 * d4);

  const int b = bh >> 3, h = bh & 7;
  const int orow = (8 + vg) * 128 + row;
  float4 o;
  o.x = (a0.x * e0 + a1.x * e1) * inv;
  o.y = (a0.y * e0 + a1.y * e1) * inv;
  o.z = (a0.z * e0 + a1.z * e1) * inv;
  o.w = (a0.w * e0 + a1.w * e1) * inv;
  *(float4*)(O + ((size_t)(b * L + orow) * H + h) * E + 4 * d4) = o;
}

} // namespace

extern "C" void kernel_launch(void* const* d_in, const int* in_sizes, int n_in,
                              void* d_out, int out_size, void* d_ws, size_t ws_size,
                              hipStream_t stream) {
  const float* Q = (const float*)d_in[0];
  const float* K = (const float*)d_in[1];
  const float* V = (const float*)d_in[2];
  float* O = (float*)d_out;
  (void)in_sizes; (void)n_in; (void)out_size;

  const bool split = ws_size >= PART_FLOATS * sizeof(float);
  if (split) {
    fa_split<<<512, 512, 0, stream>>>(Q, K, V, O, (float*)d_ws, 1);
    fa_merge<<<2048, 256, 0, stream>>>((const float*)d_ws, O);
  } else {
    fa_split<<<256, 512, 0, stream>>>(Q, K, V, O, (float*)d_ws, 0);
  }
}